// Round 5
// baseline (499.148 us; speedup 1.0000x reference)
//
#include <hip/hip_runtime.h>
#include <hip/hip_bf16.h>
#include <cstddef>

#define GN 50000
#define GE 800000
#define GH 4
#define GD 32
#define SLOPE 0.2f

typedef unsigned short ushort_t;
typedef unsigned int uint_t;
using short8 = __attribute__((ext_vector_type(8))) short;
using float4v = __attribute__((ext_vector_type(4))) float;

__device__ __forceinline__ ushort_t f2bf(float f) {
    union { float f; uint_t u; } v; v.f = f;
    uint_t r = v.u + 0x7fff + ((v.u >> 16) & 1);   // RNE
    return (ushort_t)(r >> 16);
}
__device__ __forceinline__ float bflo(uint_t u) { return __uint_as_float(u << 16); }
__device__ __forceinline__ float bfhi(uint_t u) { return __uint_as_float(u & 0xffff0000u); }

// ---------------- CSR build ----------------
__global__ void k_hist(const int* __restrict__ dst, int* __restrict__ deg, int E) {
    int i = blockIdx.x * 256 + threadIdx.x;
    if (i < E) atomicAdd(&deg[dst[i]], 1);
}

__global__ void k_scan1(const int* __restrict__ deg, int* __restrict__ row_ptr,
                        int* __restrict__ partials, int n) {
    __shared__ int s[256];
    int t = threadIdx.x;
    int i = blockIdx.x * 256 + t;
    int v = (i < n) ? deg[i] : 0;
    s[t] = v;
    __syncthreads();
    for (int off = 1; off < 256; off <<= 1) {
        int add = (t >= off) ? s[t - off] : 0;
        __syncthreads();
        s[t] += add;
        __syncthreads();
    }
    if (i < n) row_ptr[i] = s[t] - v;
    if (t == 255) partials[blockIdx.x] = s[255];
}

__global__ void k_scan2(int* __restrict__ partials, int nb) {
    __shared__ int s[256];
    int t = threadIdx.x;
    int v = (t < nb) ? partials[t] : 0;
    s[t] = v;
    __syncthreads();
    for (int off = 1; off < 256; off <<= 1) {
        int add = (t >= off) ? s[t - off] : 0;
        __syncthreads();
        s[t] += add;
        __syncthreads();
    }
    if (t < nb) partials[t] = s[t] - v;
}

__global__ void k_scan3(int* __restrict__ row_ptr, int* __restrict__ wpos,
                        const int* __restrict__ partials, int n, int E) {
    int i = blockIdx.x * 256 + threadIdx.x;
    if (i < n) {
        int rp = row_ptr[i] + partials[i >> 8];
        row_ptr[i] = rp;
        wpos[i] = rp;
        if (i == 0) row_ptr[n] = E;
    }
}

__global__ void k_fill(const int* __restrict__ src, const int* __restrict__ dst,
                       int* __restrict__ wpos, int2* __restrict__ csr_sd, int E) {
    int i = blockIdx.x * 256 + threadIdx.x;
    if (i < E) {
        int d = dst[i];
        int p = atomicAdd(&wpos[d], 1);
        csr_sd[p] = make_int2(src[i], d);
    }
}

// ---------------- weight transpose+convert ----------------
__global__ void k_cvt_w(const float* __restrict__ W0, const float* __restrict__ W1,
                        ushort_t* __restrict__ wbt) {
    int t = blockIdx.x * 256 + threadIdx.x;   // 0..32767
    int m = t >> 14;
    int o = t & 16383;
    int n = o >> 7, k = o & 127;
    const float* W = m ? W1 : W0;
    wbt[t] = f2bf(W[k * 128 + n]);
}

// ---------------- MFMA GEMM (fp32 A, layer 1): Cb = [A0;A1] @ W ----------------
// 128 rows per block; wave handles 2 row-tiles of 16
__global__ __launch_bounds__(256) void gemm_mfma32(const float* __restrict__ A0,
                                                   const float* __restrict__ A1,
                                                   const ushort_t* __restrict__ WbT,
                                                   ushort_t* __restrict__ Cb, int M) {
    __shared__ ushort_t Bs[128][136];
    int tid = threadIdx.x;
    for (int i = tid; i < 128 * 16; i += 256) {
        int n = i >> 4;
        int kc = (i & 15) << 3;
        *(short8*)&Bs[n][kc] = *(const short8*)&WbT[n * 128 + kc];
    }
    __syncthreads();
    int wid = tid >> 6, lane = tid & 63;
    int r0 = blockIdx.x * 128 + wid * 32;
    int col = lane & 15, quad = lane >> 4;
    float4v acc[2][8];
#pragma unroll
    for (int rt = 0; rt < 2; rt++)
#pragma unroll
        for (int t = 0; t < 8; t++) acc[rt][t] = (float4v){0.f, 0.f, 0.f, 0.f};
    int ar[2] = {r0 + col, r0 + 16 + col};
    const float* Ap[2];
#pragma unroll
    for (int rt = 0; rt < 2; rt++) {
        int a = ar[rt];
        Ap[rt] = (a < M) ? ((a < GN) ? (A0 + (size_t)a * 128)
                                     : (A1 + (size_t)(a - GN) * 128)) : nullptr;
    }
#pragma unroll
    for (int ks = 0; ks < 4; ks++) {
        short8 af[2];
#pragma unroll
        for (int rt = 0; rt < 2; rt++) {
            af[rt] = (short8){};
            if (Ap[rt]) {
                float4 v0 = *(const float4*)&Ap[rt][ks * 32 + quad * 8];
                float4 v1 = *(const float4*)&Ap[rt][ks * 32 + quad * 8 + 4];
                af[rt][0] = (short)f2bf(v0.x); af[rt][1] = (short)f2bf(v0.y);
                af[rt][2] = (short)f2bf(v0.z); af[rt][3] = (short)f2bf(v0.w);
                af[rt][4] = (short)f2bf(v1.x); af[rt][5] = (short)f2bf(v1.y);
                af[rt][6] = (short)f2bf(v1.z); af[rt][7] = (short)f2bf(v1.w);
            }
        }
#pragma unroll
        for (int nt = 0; nt < 8; nt++) {
            short8 bf = *(const short8*)&Bs[nt * 16 + col][ks * 32 + quad * 8];
            acc[0][nt] = __builtin_amdgcn_mfma_f32_16x16x32_bf16(af[0], bf, acc[0][nt], 0, 0, 0);
            acc[1][nt] = __builtin_amdgcn_mfma_f32_16x16x32_bf16(af[1], bf, acc[1][nt], 0, 0, 0);
        }
    }
#pragma unroll
    for (int rt = 0; rt < 2; rt++)
#pragma unroll
        for (int nt = 0; nt < 8; nt++)
#pragma unroll
            for (int r = 0; r < 4; r++) {
                int row = r0 + rt * 16 + quad * 4 + r;
                if (row < M) Cb[(size_t)row * 128 + nt * 16 + col] = f2bf(acc[rt][nt][r]);
            }
}

// ---------------- MFMA GEMM (bf16 A, layer 2) ----------------
__global__ __launch_bounds__(256) void gemm_mfma(const ushort_t* __restrict__ A,
                                                 const ushort_t* __restrict__ WbT,
                                                 ushort_t* __restrict__ Cb, int M) {
    __shared__ ushort_t Bs[128][136];
    int tid = threadIdx.x;
    for (int i = tid; i < 128 * 16; i += 256) {
        int n = i >> 4;
        int kc = (i & 15) << 3;
        *(short8*)&Bs[n][kc] = *(const short8*)&WbT[n * 128 + kc];
    }
    __syncthreads();
    int wid = tid >> 6, lane = tid & 63;
    int r0 = blockIdx.x * 128 + wid * 32;
    int col = lane & 15, quad = lane >> 4;
    float4v acc[2][8];
#pragma unroll
    for (int rt = 0; rt < 2; rt++)
#pragma unroll
        for (int t = 0; t < 8; t++) acc[rt][t] = (float4v){0.f, 0.f, 0.f, 0.f};
    int ar[2] = {r0 + col, r0 + 16 + col};
#pragma unroll
    for (int ks = 0; ks < 4; ks++) {
        short8 af[2];
#pragma unroll
        for (int rt = 0; rt < 2; rt++) {
            af[rt] = (short8){};
            if (ar[rt] < M) af[rt] = *(const short8*)&A[(size_t)ar[rt] * 128 + ks * 32 + quad * 8];
        }
#pragma unroll
        for (int nt = 0; nt < 8; nt++) {
            short8 bf = *(const short8*)&Bs[nt * 16 + col][ks * 32 + quad * 8];
            acc[0][nt] = __builtin_amdgcn_mfma_f32_16x16x32_bf16(af[0], bf, acc[0][nt], 0, 0, 0);
            acc[1][nt] = __builtin_amdgcn_mfma_f32_16x16x32_bf16(af[1], bf, acc[1][nt], 0, 0, 0);
        }
    }
#pragma unroll
    for (int rt = 0; rt < 2; rt++)
#pragma unroll
        for (int nt = 0; nt < 8; nt++)
#pragma unroll
            for (int r = 0; r < 4; r++) {
                int row = r0 + rt * 16 + quad * 4 + r;
                if (row < M) Cb[(size_t)row * 128 + nt * 16 + col] = f2bf(acc[rt][nt][r]);
            }
}

// ---------------- attention logits el/er (bf16 feat) ----------------
__global__ void compute_lr(const ushort_t* __restrict__ featb,
                           const float* __restrict__ al, const float* __restrict__ ar,
                           float* __restrict__ el, float* __restrict__ er, int NPH) {
    int i = blockIdx.x * 256 + threadIdx.x;   // i = p*H + h
    if (i >= NPH) return;
    int h = i & (GH - 1);
    const uint_t* f = (const uint_t*)(featb + (size_t)(i >> 2) * 128 + h * GD);
    const float* a = al + h * GD;
    const float* b = ar + h * GD;
    float sl = 0.f, sr = 0.f;
#pragma unroll
    for (int q = 0; q < 16; q++) {
        uint_t u = f[q];
        float x = bflo(u), y = bfhi(u);
        sl += x * a[2 * q] + y * a[2 * q + 1];
        sr += x * b[2 * q] + y * b[2 * q + 1];
    }
    el[i] = sl;
    er[i] = sr;
}

// ---------------- per-edge softmax weights, 1 thread = 1 edge, 4 heads ----------------
__device__ __forceinline__ uint_t pk2(float e0, float e1) {
    e0 = e0 > 0.f ? e0 : SLOPE * e0;
    e1 = e1 > 0.f ? e1 : SLOPE * e1;
    return ((uint_t)f2bf(__expf(e1)) << 16) | (uint_t)f2bf(__expf(e0));
}

__global__ void k_weights2(const int2* __restrict__ csr_sd,
                           const float* __restrict__ el, const float* __restrict__ er,
                           uint_t* __restrict__ aw, int E) {
    int j = blockIdx.x * 256 + threadIdx.x;
    if (j >= E) return;
    int2 sd = csr_sd[j];
    float4 l0 = *(const float4*)&el[(size_t)sd.x * 4];
    float4 r0 = *(const float4*)&er[(size_t)sd.y * 4];
    float4 l1 = *(const float4*)&el[((size_t)sd.x + GN) * 4];
    float4 r1 = *(const float4*)&er[((size_t)sd.y + GN) * 4];
    uint4 o;
    o.x = pk2(l0.x + r0.x, l1.x + r1.x);
    o.y = pk2(l0.y + r0.y, l1.y + r1.y);
    o.z = pk2(l0.z + r0.z, l1.z + r1.z);
    o.w = pk2(l0.w + r0.w, l1.w + r1.w);
    *(uint4*)&aw[(size_t)j * 4] = o;
}

// ---------------- aggregate: one wave per node; lanes 0-31 path0, 32-63 path1 ----------------
// lane covers dims 4q..4q+3 (q=lane&31); head = q>>3
__global__ __launch_bounds__(256) void gat_agg4(
    const ushort_t* __restrict__ featb, const uint_t* __restrict__ aw,
    const int* __restrict__ row_ptr, const int2* __restrict__ csr_sd,
    float* __restrict__ io, ushort_t* __restrict__ iob, int use_resid) {
    int n = blockIdx.x * 4 + (threadIdx.x >> 6);
    if (n >= GN) return;
    int lane = threadIdx.x & 63;
    int half = lane >> 5;
    int q = lane & 31;
    int hh = q >> 3;
    const ushort_t* fb = featb + (size_t)half * GN * 128;
    int base = row_ptr[n];
    int deg = row_ptr[n + 1] - base;
    float acc0 = 0.f, acc1 = 0.f, acc2 = 0.f, acc3 = 0.f, ssum = 0.f;
    int q4 = q << 2;

    for (int c = 0; c < deg; c += 16) {
        int cnt = deg - c;
        if (cnt > 16) cnt = 16;
        // one coalesced index load + one coalesced weight load per 16 edges
        int sreg = csr_sd[base + c + (lane & 15)].x;               // lane t: edge c+t (t<16)
        uint_t wreg = aw[(size_t)(base + c) * 4 + lane];           // lane t: edge c+t/4, head t&3
#pragma unroll
        for (int e = 0; e < 16; e++) {
            if (e >= cnt) break;
            int s_e = __shfl(sreg, e);
            uint_t wp = __shfl(wreg, e * 4 + hh);
            float w = half ? bfhi(wp) : bflo(wp);
            uint2 fv = *(const uint2*)&fb[(size_t)s_e * 128 + q4];
            ssum += w;
            acc0 += w * bflo(fv.x);
            acc1 += w * bfhi(fv.x);
            acc2 += w * bflo(fv.y);
            acc3 += w * bfhi(fv.y);
        }
    }
    float inv = (deg > 0) ? 1.f / ssum : 0.f;
    float v0 = acc0 * inv, v1 = acc1 * inv, v2 = acc2 * inv, v3 = acc3 * inv;
    size_t idx = ((size_t)n + (size_t)half * GN) * 128 + q4;
    if (use_resid) {
        float4 r = *(const float4*)&io[idx];
        v0 += r.x; v1 += r.y; v2 += r.z; v3 += r.w;
    }
    v0 = v0 > 0.f ? v0 : __expf(v0) - 1.f;
    v1 = v1 > 0.f ? v1 : __expf(v1) - 1.f;
    v2 = v2 > 0.f ? v2 : __expf(v2) - 1.f;
    v3 = v3 > 0.f ? v3 : __expf(v3) - 1.f;
    *(float4*)&io[idx] = make_float4(v0, v1, v2, v3);
    if (iob) {
        ushort4 o;
        o.x = f2bf(v0); o.y = f2bf(v1); o.z = f2bf(v2); o.w = f2bf(v3);
        *(ushort4*)&iob[idx] = o;
    }
}

// ---------------- mixup + output projection (Wout staged in LDS) ----------------
__global__ __launch_bounds__(256) void out_mix(const float* __restrict__ hbuf,
                                               const float* __restrict__ Wout,
                                               const float* __restrict__ bout,
                                               const float* __restrict__ lamb,
                                               float* __restrict__ outh,
                                               float* __restrict__ outlog, int Nn) {
    __shared__ float Ws[128 * 40];
    __shared__ float bs[40];
    __shared__ float hs[4][128];
    int tid = threadIdx.x;
    for (int i = tid; i < 128 * 40; i += 256) Ws[i] = Wout[i];
    if (tid < 40) bs[tid] = bout[tid];
    float lam = lamb[0];
    int w = tid >> 6, lane = tid & 63;
    __syncthreads();
    for (int node = blockIdx.x * 4 + w; node < Nn; node += 512 * 4) {
        size_t i1 = (size_t)node * 128 + (lane << 1);
        size_t i2 = (size_t)(node + GN) * 128 + (lane << 1);
        float2 a = *(const float2*)&hbuf[i1];
        float2 b = *(const float2*)&hbuf[i2];
        float m0 = lam * a.x + (1.f - lam) * b.x;
        float m1 = lam * a.y + (1.f - lam) * b.y;
        *(float2*)&outh[i1] = make_float2(m0, m1);
        hs[w][lane * 2] = m0;
        hs[w][lane * 2 + 1] = m1;
        // same-wave LDS write→read: no barrier needed
        if (lane < 40) {
            float acc = bs[lane];
#pragma unroll 4
            for (int k = 0; k < 128; k++) acc += hs[w][k] * Ws[k * 40 + lane];
            outlog[(size_t)node * 40 + lane] = acc;
        }
    }
}

extern "C" void kernel_launch(void* const* d_in, const int* in_sizes, int n_in,
                              void* d_out, int out_size, void* d_ws, size_t ws_size,
                              hipStream_t stream) {
    const float* inputs = (const float*)d_in[0];
    const float* target = (const float*)d_in[1];
    const float* lamb   = (const float*)d_in[2];
    const float* W0     = (const float*)d_in[3];
    const float* al0    = (const float*)d_in[4];
    const float* ar0    = (const float*)d_in[5];
    const float* W1     = (const float*)d_in[6];
    const float* al1    = (const float*)d_in[7];
    const float* ar1    = (const float*)d_in[8];
    const float* Wout   = (const float*)d_in[9];
    const float* bout   = (const float*)d_in[10];
    const int*   src    = (const int*)d_in[11];
    const int*   dst    = (const int*)d_in[12];

    float* out = (float*)d_out;
    float* outh = out;                          // [N,128]
    float* outlog = out + (size_t)GN * 128;     // [N,40]

    const int NP = 2 * GN;
    // workspace layout
    ushort_t* featb = (ushort_t*)d_ws;                    // [2N,128] bf16
    ushort_t* abuf  = featb + (size_t)NP * 128;           // [2N,128] bf16 (layer1 agg out)
    float* t0 = (float*)(abuf + (size_t)NP * 128);        // [2N,128] fp32
    float* el = t0 + (size_t)NP * 128;                    // [2N,4]
    float* er = el + (size_t)NP * GH;                     // [2N,4]
    uint_t* aw = (uint_t*)(er + (size_t)NP * GH);         // [E,4] bf16x2 packed (+64 pad)
    ushort_t* wbt = (ushort_t*)(aw + (size_t)GE * 4 + 64);// [2][128][128] bf16
    int* row_ptr  = (int*)(wbt + 2 * 128 * 128);          // N+1
    int* wpos     = row_ptr + (GN + 1);                   // N
    int2* csr_sd  = (int2*)(wpos + GN);                   // E (+16 pad)
    int* partials = (int*)(csr_sd + GE + 16);             // 256

    const int NPH = NP * GH;
    const int nb = (GN + 255) / 256;
    const int eb = (GE + 255) / 256;
    const int gblocks = (NP + 127) / 128;
    const int lrblocks = (NPH + 255) / 256;
    const int aggblocks = (GN + 3) / 4;

    // ---- CSR build ----
    hipMemsetAsync(wpos, 0, GN * sizeof(int), stream);
    k_hist<<<eb, 256, 0, stream>>>(dst, wpos, GE);
    k_scan1<<<nb, 256, 0, stream>>>(wpos, row_ptr, partials, GN);
    k_scan2<<<1, 256, 0, stream>>>(partials, nb);
    k_scan3<<<nb, 256, 0, stream>>>(row_ptr, wpos, partials, GN, GE);
    k_fill<<<eb, 256, 0, stream>>>(src, dst, wpos, csr_sd, GE);

    // ---- weights convert ----
    k_cvt_w<<<128, 256, 0, stream>>>(W0, W1, wbt);

    // ---- layer 1 ----
    gemm_mfma32<<<gblocks, 256, 0, stream>>>(inputs, target, wbt, featb, NP);
    compute_lr<<<lrblocks, 256, 0, stream>>>(featb, al0, ar0, el, er, NPH);
    k_weights2<<<eb, 256, 0, stream>>>(csr_sd, el, er, aw, GE);
    gat_agg4<<<aggblocks, 256, 0, stream>>>(featb, aw, row_ptr, csr_sd,
                                            t0, abuf, 0);

    // ---- layer 2 ----
    gemm_mfma<<<gblocks, 256, 0, stream>>>(abuf, wbt + 128 * 128, featb, NP);
    compute_lr<<<lrblocks, 256, 0, stream>>>(featb, al1, ar1, el, er, NPH);
    k_weights2<<<eb, 256, 0, stream>>>(csr_sd, el, er, aw, GE);
    gat_agg4<<<aggblocks, 256, 0, stream>>>(featb, aw, row_ptr, csr_sd,
                                            t0, nullptr, 1);

    // ---- mixup + projection ----
    out_mix<<<512, 256, 0, stream>>>(t0, Wout, bout, lamb, outh, outlog, GN);
}